// Round 6
// baseline (617.962 us; speedup 1.0000x reference)
//
#include <hip/hip_runtime.h>
#include <hip/hip_bf16.h>

// MultiheadAttention_ViTNO: B=8, P=256, S=8x8(=64), D=256, NHEAD=8, DK=32, SCALE=64
// R6: (a) k_cvt converts x to bf16 once; k1 reads bf16 x GLOBAL-DIRECT (no LDS,
// no barrier, 8-wave blocks, acc[4][2]) — kills the 3x fp32 re-read that made
// R5-k1 2x its HBM floor. (b) Occupancy fix applied to tail: k2a p-tile 16
// (grid 1024), k2b p32/c256 (grid 4096), k3 t32 (grid 4096). R5 lesson: small
// per-wave state + enough blocks/CU is the whole game on this problem.

typedef __bf16 bf16;
typedef __attribute__((ext_vector_type(8))) __bf16 bf16x8;
typedef __attribute__((ext_vector_type(4))) float floatx4;
typedef __attribute__((ext_vector_type(8))) unsigned short ushort8;

#define CDIM 2048             // 64*32 flattened (sxy, dk) per head

static __device__ __forceinline__ floatx4 mfma16(bf16x8 a, bf16x8 b, floatx4 c) {
  return __builtin_amdgcn_mfma_f32_16x16x32_bf16(a, b, c, 0, 0, 0);
}

// ---------------- K0: weight prep ----------------
// Wp: fragment-linear pack of Wq/Wk/Wv (head-permuted rows i'=n*32+dk):
//   Wp[((mat*8 + kk)*16 + rowblk)*64 + lane]*8 ; lane=(h,cl):
//   element = Wperm[rowblk*16+cl][kk*32+8h+j]
// WOp: row-major [j][i'-permuted col] for k3. biasp[3][256] permuted.
__global__ __launch_bounds__(256) void k0_prep(
    const float* __restrict__ Wq, const float* __restrict__ bq,
    const float* __restrict__ Wk, const float* __restrict__ bk,
    const float* __restrict__ Wv, const float* __restrict__ bv,
    const float* __restrict__ Wo,
    bf16* __restrict__ Wp, bf16* __restrict__ WOp, float* __restrict__ biasp)
{
  const int bid = blockIdx.x, tid = threadIdx.x;
  if (bid < 32) {
    int g = bid * 256 + tid;            // 0..8191 : (kk, rowblk, lane)
    int lane = g & 63, rowblk = (g >> 6) & 15, kk = g >> 10;
    int h = lane >> 4, cl = lane & 15;
    int ip = rowblk * 16 + cl;          // i' = n*32+dk
    int isrc = ((ip & 31) << 3) | (ip >> 5);
    int d0 = kk * 32 + 8 * h;
#pragma unroll
    for (int mat = 0; mat < 3; mat++) {
      const float* W = (mat == 0) ? Wq : (mat == 1) ? Wk : Wv;
      bf16x8 v;
#pragma unroll
      for (int j = 0; j < 8; j++) v[j] = (bf16)W[isrc * 256 + d0 + j];
      *reinterpret_cast<bf16x8*>(Wp + ((size_t)mat * 8192 + g) * 8) = v;
    }
  } else {
    int g = (bid - 32) * 256 + tid;     // 0..8191
    int row = g >> 5;
    int c0 = (g & 31) * 8;
#pragma unroll
    for (int j = 0; j < 8; j++) {
      int c = c0 + j;
      WOp[row * 256 + c] = (bf16)Wo[row * 256 + (((c & 31) << 3) | (c >> 5))];
    }
    if (g < 256) {
      int bs = ((g & 31) << 3) | (g >> 5);
      biasp[g] = bq[bs]; biasp[256 + g] = bk[bs]; biasp[512 + g] = bv[bs];
    }
  }
}

// ---------------- K_cvt: x fp32 -> bf16 (token-major, same layout) ----------------
__global__ __launch_bounds__(256) void k_cvt(
    const float* __restrict__ x, bf16* __restrict__ xb)
{
  size_t i = ((size_t)blockIdx.x * 256 + threadIdx.x) * 8;
  floatx4 f0 = *reinterpret_cast<const floatx4*>(x + i);
  floatx4 f1 = *reinterpret_cast<const floatx4*>(x + i + 4);
  bf16x8 v;
#pragma unroll
  for (int j = 0; j < 4; j++) { v[j] = (bf16)f0[j]; v[4 + j] = (bf16)f1[j]; }
  *reinterpret_cast<bf16x8*>(xb + i) = v;
}

// ---------------- K1: QKV projection, bf16-source, global-direct ----------------
// grid (2048, 3); block 512 (8 waves, each a 32-col slice). Tile: 64 tokens.
// No LDS, no barrier. Out token-major: Q/K/V[t][i'] bf16.
__global__ __launch_bounds__(512, 6) void k1_qkv_bf(
    const bf16* __restrict__ xb, const bf16* __restrict__ Wp,
    const float* __restrict__ biasp,
    bf16* __restrict__ Qt, bf16* __restrict__ Kt, bf16* __restrict__ Vt)
{
  const int t0 = blockIdx.x * 64;
  const int mat = blockIdx.y;
  const int tid = threadIdx.x;
  const int lane = tid & 63;
  const int w = tid >> 6;               // wave 0..7 -> ip slice [w*32, w*32+32)
  const int h = lane >> 4, cl = lane & 15;

  const bf16* Wm = Wp + (size_t)mat * 65536;
  bf16* out = (mat == 0) ? Qt : (mat == 1) ? Kt : Vt;

  floatx4 acc[4][2];
#pragma unroll
  for (int i = 0; i < 4; i++)
#pragma unroll
    for (int j = 0; j < 2; j++) acc[i][j] = (floatx4)0.0f;

#pragma unroll 2
  for (int kk = 0; kk < 8; ++kk) {
    bf16x8 a[4];
#pragma unroll
    for (int mt = 0; mt < 4; mt++)
      a[mt] = *reinterpret_cast<const bf16x8*>(
          xb + (size_t)(t0 + mt * 16 + cl) * 256 + kk * 32 + 8 * h);
    bf16x8 b0 = *reinterpret_cast<const bf16x8*>(
        Wm + ((size_t)(kk * 16 + w * 2 + 0) * 64 + lane) * 8);
    bf16x8 b1 = *reinterpret_cast<const bf16x8*>(
        Wm + ((size_t)(kk * 16 + w * 2 + 1) * 64 + lane) * 8);
#pragma unroll
    for (int mt = 0; mt < 4; mt++) acc[mt][0] = mfma16(a[mt], b0, acc[mt][0]);
#pragma unroll
    for (int mt = 0; mt < 4; mt++) acc[mt][1] = mfma16(a[mt], b1, acc[mt][1]);
  }

#pragma unroll
  for (int nt = 0; nt < 2; nt++) {
    const int ip = w * 32 + nt * 16 + cl;
    const float bb = biasp[mat * 256 + ip];
#pragma unroll
    for (int mt = 0; mt < 4; mt++)
#pragma unroll
      for (int r = 0; r < 4; r++) {
        int t = t0 + mt * 16 + 4 * h + r;
        out[(size_t)t * 256 + ip] = (bf16)(acc[mt][nt][r] + bb);
      }
  }
}

// Fallback (small ws): same structure, fp32 source with in-loop cvt.
__global__ __launch_bounds__(512, 6) void k1_qkv_f32(
    const float* __restrict__ x, const bf16* __restrict__ Wp,
    const float* __restrict__ biasp,
    bf16* __restrict__ Qt, bf16* __restrict__ Kt, bf16* __restrict__ Vt)
{
  const int t0 = blockIdx.x * 64;
  const int mat = blockIdx.y;
  const int tid = threadIdx.x;
  const int lane = tid & 63;
  const int w = tid >> 6;
  const int h = lane >> 4, cl = lane & 15;

  const bf16* Wm = Wp + (size_t)mat * 65536;
  bf16* out = (mat == 0) ? Qt : (mat == 1) ? Kt : Vt;

  floatx4 acc[4][2];
#pragma unroll
  for (int i = 0; i < 4; i++)
#pragma unroll
    for (int j = 0; j < 2; j++) acc[i][j] = (floatx4)0.0f;

#pragma unroll 2
  for (int kk = 0; kk < 8; ++kk) {
    bf16x8 a[4];
#pragma unroll
    for (int mt = 0; mt < 4; mt++) {
      const float* sp = x + (size_t)(t0 + mt * 16 + cl) * 256 + kk * 32 + 8 * h;
      floatx4 f0 = *reinterpret_cast<const floatx4*>(sp);
      floatx4 f1 = *reinterpret_cast<const floatx4*>(sp + 4);
      bf16x8 av;
#pragma unroll
      for (int j = 0; j < 4; j++) { av[j] = (bf16)f0[j]; av[4 + j] = (bf16)f1[j]; }
      a[mt] = av;
    }
    bf16x8 b0 = *reinterpret_cast<const bf16x8*>(
        Wm + ((size_t)(kk * 16 + w * 2 + 0) * 64 + lane) * 8);
    bf16x8 b1 = *reinterpret_cast<const bf16x8*>(
        Wm + ((size_t)(kk * 16 + w * 2 + 1) * 64 + lane) * 8);
#pragma unroll
    for (int mt = 0; mt < 4; mt++) acc[mt][0] = mfma16(a[mt], b0, acc[mt][0]);
#pragma unroll
    for (int mt = 0; mt < 4; mt++) acc[mt][1] = mfma16(a[mt], b1, acc[mt][1]);
  }

#pragma unroll
  for (int nt = 0; nt < 2; nt++) {
    const int ip = w * 32 + nt * 16 + cl;
    const float bb = biasp[mat * 256 + ip];
#pragma unroll
    for (int mt = 0; mt < 4; mt++)
#pragma unroll
      for (int r = 0; r < 4; r++) {
        int t = t0 + mt * 16 + 4 * h + r;
        out[(size_t)t * 256 + ip] = (bf16)(acc[mt][nt][r] + bb);
      }
  }
}

// ---------------- K2a: scores + softmax ----------------
// grid 1024 (= 64 bn * 16 ptiles of 16); block 256 (4 waves = q quadrants).
__global__ __launch_bounds__(256) void k2a_scores(
    const bf16* __restrict__ Qt, const bf16* __restrict__ Kt,
    bf16* __restrict__ attn)
{
  const int bx = blockIdx.x;
  const int bn = bx >> 4;
  const int p0 = (bx & 15) * 16;
  const int b = bn >> 3, n = bn & 7;
  const int lane = threadIdx.x & 63;
  const int wv = threadIdx.x >> 6;
  const int h = lane >> 4, cl = lane & 15;

  const bf16* qp = Qt + (size_t)((b * 256 + p0 + cl) * 64) * 256 + n * 32 + 8 * h;
  const bf16* kp[4];
#pragma unroll
  for (int nt = 0; nt < 4; nt++)
    kp[nt] = Kt + (size_t)((b * 256 + 64 * wv + nt * 16 + cl) * 64) * 256 + n * 32 + 8 * h;

  floatx4 acc[4];
#pragma unroll
  for (int j = 0; j < 4; j++) acc[j] = (floatx4)0.0f;

#pragma unroll 4
  for (int ks = 0; ks < 64; ks++) {
    bf16x8 a = *reinterpret_cast<const bf16x8*>(qp); qp += 256;
    bf16x8 bb[4];
#pragma unroll
    for (int nt = 0; nt < 4; nt++) {
      bb[nt] = *reinterpret_cast<const bf16x8*>(kp[nt]); kp[nt] += 256;
    }
#pragma unroll
    for (int nt = 0; nt < 4; nt++) acc[nt] = mfma16(a, bb[nt], acc[nt]);
  }

  // softmax over q. Rows held: 4h + r (16 rows). Cols: 64*wv + nt*16 + cl.
  __shared__ float redmax[4][16];
  __shared__ float redsum[4][16];

  float pm[4];
#pragma unroll
  for (int r = 0; r < 4; r++)
    pm[r] = fmaxf(fmaxf(acc[0][r], acc[1][r]), fmaxf(acc[2][r], acc[3][r]));
#pragma unroll
  for (int off = 1; off < 16; off <<= 1)
#pragma unroll
    for (int r = 0; r < 4; r++)
      pm[r] = fmaxf(pm[r], __shfl_xor(pm[r], off, 64));
  if (cl == 0) {
#pragma unroll
    for (int r = 0; r < 4; r++) redmax[wv][4 * h + r] = pm[r];
  }
  __syncthreads();

  float gm[4], ps[4];
#pragma unroll
  for (int r = 0; r < 4; r++) {
    int row = 4 * h + r;
    gm[r] = fmaxf(fmaxf(redmax[0][row], redmax[1][row]),
                  fmaxf(redmax[2][row], redmax[3][row]));
    ps[r] = 0.0f;
  }
  const float KS = 1.44269504088896340736f / 64.0f;   // log2(e)/SCALE
#pragma unroll
  for (int nt = 0; nt < 4; nt++)
#pragma unroll
    for (int r = 0; r < 4; r++) {
      float e = exp2f((acc[nt][r] - gm[r]) * KS);
      acc[nt][r] = e;
      ps[r] += e;
    }
#pragma unroll
  for (int off = 1; off < 16; off <<= 1)
#pragma unroll
    for (int r = 0; r < 4; r++) ps[r] += __shfl_xor(ps[r], off, 64);
  if (cl == 0) {
#pragma unroll
    for (int r = 0; r < 4; r++) redsum[wv][4 * h + r] = ps[r];
  }
  __syncthreads();

#pragma unroll
  for (int r = 0; r < 4; r++) {
    int row = 4 * h + r;
    float gs = redsum[0][row] + redsum[1][row] + redsum[2][row] + redsum[3][row];
    ps[r] = 1.0f / gs;
  }
#pragma unroll
  for (int nt = 0; nt < 4; nt++) {
    int q = 64 * wv + nt * 16 + cl;
#pragma unroll
    for (int r = 0; r < 4; r++) {
      int row = p0 + 4 * h + r;
      attn[(size_t)bn * 65536 + row * 256 + q] = (bf16)(acc[nt][r] * ps[r]);
    }
  }
}

// ---------------- K2t: V transpose (token-major V -> Vq[bn][c][q]) ----------------
__global__ __launch_bounds__(256) void k2t_transpose(
    const bf16* __restrict__ Vtok, bf16* __restrict__ Vq)
{
  const int bx = blockIdx.x;
  const int bn = bx >> 7;
  const int q0 = ((bx >> 5) & 3) * 64;
  const int c0 = (bx & 31) * 64;           // c = sxy*32 + dk
  const int b = bn >> 3, n = bn & 7;
  __shared__ unsigned short tile[64][65];
  const unsigned short* src = (const unsigned short*)Vtok;
  unsigned short* dst = (unsigned short*)Vq + (size_t)bn * 524288;
  {
    const int q = threadIdx.x >> 3;            // 0..31
    const int cj = (threadIdx.x & 7) * 8;
    const int c = c0 + cj;
    const int sxy = c >> 5, dk0 = c & 31;
#pragma unroll
    for (int it = 0; it < 2; ++it) {
      int qq = q + it * 32;
      size_t sa = (size_t)((b * 256 + q0 + qq) * 64 + sxy) * 256 + n * 32 + dk0;
      ushort8 s = *reinterpret_cast<const ushort8*>(src + sa);
#pragma unroll
      for (int j = 0; j < 8; j++) tile[qq][cj + j] = s[j];
    }
  }
  __syncthreads();
  {
    const int crow = threadIdx.x >> 2;         // 0..63
    const int qj = (threadIdx.x & 3) * 8;
#pragma unroll
    for (int it = 0; it < 2; ++it) {
      int qq = qj + it * 32;
      ushort8 sv;
#pragma unroll
      for (int j = 0; j < 8; j++) sv[j] = tile[qq + j][crow];
      *reinterpret_cast<ushort8*>(dst + (size_t)(c0 + crow) * 256 + q0 + qq) = sv;
    }
  }
}

// ---------------- K2b: O = attn @ V ----------------
// grid 4096 (= 64 bn * 8 ptiles of 32 * 8 ctiles of 256); block 256.
__global__ __launch_bounds__(256) void k2b_pv(
    const bf16* __restrict__ attn, const bf16* __restrict__ Vq,
    bf16* __restrict__ yhat)
{
  const int bx = blockIdx.x;
  const int bn = bx >> 6;
  const int p0 = ((bx >> 3) & 7) * 32;
  const int c0 = (bx & 7) * 256;
  const int b = bn >> 3, n = bn & 7;
  const int lane = threadIdx.x & 63;
  const int wv = threadIdx.x >> 6;
  const int h = lane >> 4, cl = lane & 15;

  const bf16* Ab = attn + (size_t)bn * 65536;
  const bf16* Vb = Vq + (size_t)bn * 524288;

  floatx4 acc[2][4];
#pragma unroll
  for (int i = 0; i < 2; i++)
#pragma unroll
    for (int j = 0; j < 4; j++) acc[i][j] = (floatx4)0.0f;

  for (int q0 = 0; q0 < 256; q0 += 32) {
    bf16x8 a[2];
#pragma unroll
    for (int mt = 0; mt < 2; mt++)
      a[mt] = *reinterpret_cast<const bf16x8*>(Ab + (size_t)(p0 + mt * 16 + cl) * 256 + q0 + 8 * h);
#pragma unroll
    for (int nt = 0; nt < 4; nt++) {
      bf16x8 b8 = *reinterpret_cast<const bf16x8*>(Vb + (size_t)(c0 + 64 * wv + nt * 16 + cl) * 256 + q0 + 8 * h);
#pragma unroll
      for (int mt = 0; mt < 2; mt++) acc[mt][nt] = mfma16(a[mt], b8, acc[mt][nt]);
    }
  }

#pragma unroll
  for (int nt = 0; nt < 4; nt++) {
    const int cg = c0 + 64 * wv + nt * 16 + cl;
    const int dk = cg & 31, sxy = cg >> 5;
#pragma unroll
    for (int mt = 0; mt < 2; mt++)
#pragma unroll
      for (int r = 0; r < 4; r++) {
        int p = p0 + mt * 16 + 4 * h + r;
        size_t t = (size_t)((b * 256 + p) * 64) + sxy;
        yhat[t * 256 + n * 32 + dk] = (bf16)acc[mt][nt][r];
      }
  }
}

// ---------------- K3: output projection ----------------
// grid 4096 (t-tile 32); block 256.
__global__ __launch_bounds__(256) void k3_out(
    const bf16* __restrict__ yhat, const bf16* __restrict__ Wo,
    const float* __restrict__ bo, float* __restrict__ outp)
{
  const int t0 = blockIdx.x * 32;
  const int lane = threadIdx.x & 63;
  const int wv = threadIdx.x >> 6;
  const int h = lane >> 4, cl = lane & 15;

  floatx4 acc[2][4];
#pragma unroll
  for (int i = 0; i < 2; i++)
#pragma unroll
    for (int j = 0; j < 4; j++) acc[i][j] = (floatx4)0.0f;

  for (int k0 = 0; k0 < 256; k0 += 32) {
    bf16x8 a[2];
#pragma unroll
    for (int mt = 0; mt < 2; mt++)
      a[mt] = *reinterpret_cast<const bf16x8*>(yhat + (size_t)(t0 + mt * 16 + cl) * 256 + k0 + 8 * h);
#pragma unroll
    for (int nt = 0; nt < 4; nt++) {
      bf16x8 b8 = *reinterpret_cast<const bf16x8*>(Wo + (size_t)(64 * wv + nt * 16 + cl) * 256 + k0 + 8 * h);
#pragma unroll
      for (int mt = 0; mt < 2; mt++) acc[mt][nt] = mfma16(a[mt], b8, acc[mt][nt]);
    }
  }

#pragma unroll
  for (int nt = 0; nt < 4; nt++) {
    const int j = 64 * wv + nt * 16 + cl;
    const float bb = bo[j];
#pragma unroll
    for (int mt = 0; mt < 2; mt++)
#pragma unroll
      for (int r = 0; r < 4; r++)
        outp[(size_t)(t0 + mt * 16 + 4 * h + r) * 256 + j] = acc[mt][nt][r] + bb;
  }
}

// ---------------- launch ----------------
extern "C" void kernel_launch(void* const* d_in, const int* in_sizes, int n_in,
                              void* d_out, int out_size, void* d_ws, size_t ws_size,
                              hipStream_t stream) {
  const float* x  = (const float*)d_in[0];
  const float* Wq = (const float*)d_in[1];
  const float* bq = (const float*)d_in[2];
  const float* Wk = (const float*)d_in[3];
  const float* bk = (const float*)d_in[4];
  const float* Wv = (const float*)d_in[5];
  const float* bv = (const float*)d_in[6];
  const float* Wo = (const float*)d_in[7];
  const float* bo = (const float*)d_in[8];
  float* outp = (float*)d_out;

  char* ws = (char*)d_ws;
  const size_t SZ_QKV = 67108864;   // 131072*256 * 2B
  size_t off = 0;
  bf16* Qt   = (bf16*)(ws + off); off += SZ_QKV;
  bf16* Kt   = (bf16*)(ws + off); off += SZ_QKV;
  bf16* Vtok = (bf16*)(ws + off); off += SZ_QKV;
  bf16* attn = (bf16*)(ws + off); off += 8388608;
  bf16* Wp   = (bf16*)(ws + off); off += 393216;   // 3 mats packed
  bf16* WOp  = (bf16*)(ws + off); off += 131072;
  float* biasp = (float*)(ws + off); off += 3072;
  const size_t base_need = off;
  bf16* xb = (bf16*)(ws + off);     // bf16 copy of x (cvt path)
  const size_t cvt_need = off + SZ_QKV;
  if (ws_size < base_need) return;  // workspace too small: bail cleanly

  bf16* yhat = Qt;                  // Qt dead after k2a
  bf16* Vq   = Kt;                  // Kt dead after k2a (k2t runs after k2a)

  k0_prep<<<64, 256, 0, stream>>>(Wq, bq, Wk, bk, Wv, bv, Wo, Wp, WOp, biasp);
  if (ws_size >= cvt_need) {
    k_cvt<<<16384, 256, 0, stream>>>(x, xb);
    k1_qkv_bf<<<dim3(2048, 3), 512, 0, stream>>>(xb, Wp, biasp, Qt, Kt, Vtok);
  } else {
    k1_qkv_f32<<<dim3(2048, 3), 512, 0, stream>>>(x, Wp, biasp, Qt, Kt, Vtok);
  }
  k2a_scores<<<1024, 256, 0, stream>>>(Qt, Kt, attn);
  k2t_transpose<<<8192, 256, 0, stream>>>(Vtok, Vq);
  k2b_pv<<<4096, 256, 0, stream>>>(attn, Vq, yhat);
  k3_out<<<4096, 256, 0, stream>>>(yhat, WOp, bo, outp);
}

// Round 7
// 375.482 us; speedup vs baseline: 1.6458x; 1.6458x over previous
//
#include <hip/hip_runtime.h>
#include <hip/hip_bf16.h>

// MultiheadAttention_ViTNO: B=8, P=256, S=8x8(=64), D=256, NHEAD=8, DK=32, SCALE=64
// R7: revert to R5 k1 (global-direct MFMA feed was a 223us regression; LDS-staged
// A + fragment-linear-packed B + small acc + full occupancy is the proven recipe).
// Port that recipe to k2b and k3 (they had the R6 disease: both operands global).
// k2a/k2t: R5 code + bn-in-low-bits index bijection (same-bn blocks -> same XCD L2).

typedef __bf16 bf16;
typedef __attribute__((ext_vector_type(8))) __bf16 bf16x8;
typedef __attribute__((ext_vector_type(4))) float floatx4;
typedef __attribute__((ext_vector_type(8))) unsigned short ushort8;

#define CDIM 2048             // 64*32 flattened (sxy, dk) per head

static __device__ __forceinline__ floatx4 mfma16(bf16x8 a, bf16x8 b, floatx4 c) {
  return __builtin_amdgcn_mfma_f32_16x16x32_bf16(a, b, c, 0, 0, 0);
}

static __device__ __forceinline__ void gload_lds16(const void* g, void* l) {
  __builtin_amdgcn_global_load_lds((const __attribute__((address_space(1))) void*)g,
                                   (__attribute__((address_space(3))) void*)l, 16, 0, 0);
}

// ---------------- K0: weight prep ----------------
// Wp: fragment-linear pack of Wq/Wk/Wv (head-permuted rows i'=n*32+dk):
//   Wp[((mat*8+kk)*16 + rowblk)*64 + lane]*8, lane=(h,cl):
//   element = Wperm[rowblk*16+cl][kk*32+8h+j],  Wperm[i'][d] = W[orig(i')][d]
// Wk3: fragment-linear pack for k3: element = Wo[jblk*16+cl][orig(kk*32+8h+j)]
// biasp[3][256] permuted. orig(c) = ((c&31)<<3)|(c>>5).
__global__ __launch_bounds__(256) void k0_prep(
    const float* __restrict__ Wq, const float* __restrict__ bq,
    const float* __restrict__ Wk, const float* __restrict__ bk,
    const float* __restrict__ Wv, const float* __restrict__ bv,
    const float* __restrict__ Wo,
    bf16* __restrict__ Wp, bf16* __restrict__ Wk3, float* __restrict__ biasp)
{
  const int bid = blockIdx.x, tid = threadIdx.x;
  int g = (bid & 31) * 256 + tid;       // 0..8191 : (kk, rowblk, lane)
  int lane = g & 63, rowblk = (g >> 6) & 15, kk = g >> 10;
  int h = lane >> 4, cl = lane & 15;
  int d0 = kk * 32 + 8 * h;
  if (bid < 32) {
    int ip = rowblk * 16 + cl;          // i' = n*32+dk
    int isrc = ((ip & 31) << 3) | (ip >> 5);
#pragma unroll
    for (int mat = 0; mat < 3; mat++) {
      const float* W = (mat == 0) ? Wq : (mat == 1) ? Wk : Wv;
      bf16x8 v;
#pragma unroll
      for (int j = 0; j < 8; j++) v[j] = (bf16)W[isrc * 256 + d0 + j];
      *reinterpret_cast<bf16x8*>(Wp + ((size_t)mat * 8192 + g) * 8) = v;
    }
    if (bid == 0 && tid < 256) {
      int bs = ((tid & 31) << 3) | (tid >> 5);
      biasp[tid] = bq[bs]; biasp[256 + tid] = bk[bs]; biasp[512 + tid] = bv[bs];
    }
  } else {
    int j = rowblk * 16 + cl;           // output col
    bf16x8 v;
#pragma unroll
    for (int jj = 0; jj < 8; jj++) {
      int c = d0 + jj;
      v[jj] = (bf16)Wo[j * 256 + (((c & 31) << 3) | (c >> 5))];
    }
    *reinterpret_cast<bf16x8*>(Wk3 + (size_t)g * 8) = v;
  }
}

// ---------------- K1: fused QKV projection (R5 structure, proven) ----------------
// grid (2048, 3); block 512 (8 waves, each a 32-col slice). Tile: 64 tokens.
__global__ __launch_bounds__(512, 6) void k1_qkv(
    const float* __restrict__ x, const bf16* __restrict__ Wp,
    const float* __restrict__ biasp,
    bf16* __restrict__ Qt, bf16* __restrict__ Kt, bf16* __restrict__ Vt)
{
  __shared__ bf16 xsb[64 * 256];        // 32KB, granule-XOR-swizzled
  const int t0 = blockIdx.x * 64;
  const int mat = blockIdx.y;
  const int tid = threadIdx.x;
  const int lane = tid & 63;
  const int w = tid >> 6;               // wave 0..7 -> ip slice [w*32, w*32+32)
  const int h = lane >> 4, cl = lane & 15;
  const int c7 = cl & 7;

  const bf16* Wm = Wp + (size_t)mat * 65536;
  bf16* out = (mat == 0) ? Qt : (mat == 1) ? Kt : Vt;

  // stage: 2048 granules (16B); granule G: row=G>>5, coalesced fp32 src,
  // cvt to bf16, write to physical granule (G&~7)|((G^row)&7)
#pragma unroll
  for (int k = 0; k < 4; ++k) {
    int G = k * 512 + tid;
    int row = G >> 5;
    const float* sp = x + (size_t)(t0 + row) * 256 + (G & 31) * 8;
    floatx4 f0 = *reinterpret_cast<const floatx4*>(sp);
    floatx4 f1 = *reinterpret_cast<const floatx4*>(sp + 4);
    bf16x8 v;
#pragma unroll
    for (int j = 0; j < 4; j++) { v[j] = (bf16)f0[j]; v[4 + j] = (bf16)f1[j]; }
    int Gp = (G & ~7) | ((G ^ row) & 7);
    *reinterpret_cast<bf16x8*>(&xsb[Gp * 8]) = v;
  }
  __syncthreads();

  floatx4 acc[4][2];
#pragma unroll
  for (int i = 0; i < 4; i++)
#pragma unroll
    for (int j = 0; j < 2; j++) acc[i][j] = (floatx4)0.0f;

#pragma unroll 2
  for (int kk = 0; kk < 8; ++kk) {
    bf16x8 a[4];
#pragma unroll
    for (int mt = 0; mt < 4; mt++) {
      int rr = mt * 16 + cl;            // rr&7 == c7
      int G = rr * 32 + kk * 4 + h;
      int Gp = (G & ~7) | ((G ^ c7) & 7);
      a[mt] = *reinterpret_cast<const bf16x8*>(&xsb[Gp * 8]);
    }
    bf16x8 b0 = *reinterpret_cast<const bf16x8*>(
        Wm + ((size_t)(kk * 16 + w * 2 + 0) * 64 + lane) * 8);
    bf16x8 b1 = *reinterpret_cast<const bf16x8*>(
        Wm + ((size_t)(kk * 16 + w * 2 + 1) * 64 + lane) * 8);
#pragma unroll
    for (int mt = 0; mt < 4; mt++) acc[mt][0] = mfma16(a[mt], b0, acc[mt][0]);
#pragma unroll
    for (int mt = 0; mt < 4; mt++) acc[mt][1] = mfma16(a[mt], b1, acc[mt][1]);
  }

#pragma unroll
  for (int nt = 0; nt < 2; nt++) {
    const int ip = w * 32 + nt * 16 + cl;
    const float bb = biasp[mat * 256 + ip];
#pragma unroll
    for (int mt = 0; mt < 4; mt++)
#pragma unroll
      for (int r = 0; r < 4; r++) {
        int t = t0 + mt * 16 + 4 * h + r;
        out[(size_t)t * 256 + ip] = (bf16)(acc[mt][nt][r] + bb);
      }
  }
}

// ---------------- K2a: scores + softmax (R5 + XCD co-location) ----------------
// grid 512; bn = bx&63 (same-bn p-tiles land on same XCD), p0 = (bx>>6)*32.
__global__ __launch_bounds__(256) void k2a_scores(
    const bf16* __restrict__ Qt, const bf16* __restrict__ Kt,
    bf16* __restrict__ attn)
{
  const int bx = blockIdx.x;
  const int bn = bx & 63;
  const int p0 = (bx >> 6) * 32;
  const int b = bn >> 3, n = bn & 7;
  const int lane = threadIdx.x & 63;
  const int wv = threadIdx.x >> 6;
  const int h = lane >> 4, cl = lane & 15;

  const bf16* qp[2];
#pragma unroll
  for (int mt = 0; mt < 2; mt++)
    qp[mt] = Qt + (size_t)((b * 256 + p0 + mt * 16 + cl) * 64) * 256 + n * 32 + 8 * h;
  const bf16* kp[4];
#pragma unroll
  for (int nt = 0; nt < 4; nt++)
    kp[nt] = Kt + (size_t)((b * 256 + 64 * wv + nt * 16 + cl) * 64) * 256 + n * 32 + 8 * h;

  floatx4 acc[2][4];
#pragma unroll
  for (int i = 0; i < 2; i++)
#pragma unroll
    for (int j = 0; j < 4; j++) acc[i][j] = (floatx4)0.0f;

#pragma unroll 4
  for (int ks = 0; ks < 64; ks++) {
    bf16x8 a[2], bb[4];
#pragma unroll
    for (int mt = 0; mt < 2; mt++) {
      a[mt] = *reinterpret_cast<const bf16x8*>(qp[mt]); qp[mt] += 256;
    }
#pragma unroll
    for (int nt = 0; nt < 4; nt++) {
      bb[nt] = *reinterpret_cast<const bf16x8*>(kp[nt]); kp[nt] += 256;
    }
#pragma unroll
    for (int nt = 0; nt < 4; nt++)
#pragma unroll
      for (int mt = 0; mt < 2; mt++) acc[mt][nt] = mfma16(a[mt], bb[nt], acc[mt][nt]);
  }

  __shared__ float redmax[4][32];
  __shared__ float redsum[4][32];

  float pm[2][4];
#pragma unroll
  for (int mt = 0; mt < 2; mt++)
#pragma unroll
    for (int r = 0; r < 4; r++)
      pm[mt][r] = fmaxf(fmaxf(acc[mt][0][r], acc[mt][1][r]),
                        fmaxf(acc[mt][2][r], acc[mt][3][r]));
#pragma unroll
  for (int off = 1; off < 16; off <<= 1)
#pragma unroll
    for (int mt = 0; mt < 2; mt++)
#pragma unroll
      for (int r = 0; r < 4; r++)
        pm[mt][r] = fmaxf(pm[mt][r], __shfl_xor(pm[mt][r], off, 64));
  if (cl == 0) {
#pragma unroll
    for (int mt = 0; mt < 2; mt++)
#pragma unroll
      for (int r = 0; r < 4; r++) redmax[wv][mt * 16 + 4 * h + r] = pm[mt][r];
  }
  __syncthreads();

  float gm[2][4], ps[2][4];
#pragma unroll
  for (int mt = 0; mt < 2; mt++)
#pragma unroll
    for (int r = 0; r < 4; r++) {
      int row = mt * 16 + 4 * h + r;
      gm[mt][r] = fmaxf(fmaxf(redmax[0][row], redmax[1][row]),
                        fmaxf(redmax[2][row], redmax[3][row]));
      ps[mt][r] = 0.0f;
    }
  const float KS = 1.44269504088896340736f / 64.0f;   // log2(e)/SCALE
#pragma unroll
  for (int mt = 0; mt < 2; mt++)
#pragma unroll
    for (int nt = 0; nt < 4; nt++)
#pragma unroll
      for (int r = 0; r < 4; r++) {
        float e = exp2f((acc[mt][nt][r] - gm[mt][r]) * KS);
        acc[mt][nt][r] = e;
        ps[mt][r] += e;
      }
#pragma unroll
  for (int off = 1; off < 16; off <<= 1)
#pragma unroll
    for (int mt = 0; mt < 2; mt++)
#pragma unroll
      for (int r = 0; r < 4; r++) ps[mt][r] += __shfl_xor(ps[mt][r], off, 64);
  if (cl == 0) {
#pragma unroll
    for (int mt = 0; mt < 2; mt++)
#pragma unroll
      for (int r = 0; r < 4; r++) redsum[wv][mt * 16 + 4 * h + r] = ps[mt][r];
  }
  __syncthreads();

#pragma unroll
  for (int mt = 0; mt < 2; mt++)
#pragma unroll
    for (int r = 0; r < 4; r++) {
      int row = mt * 16 + 4 * h + r;
      float gs = redsum[0][row] + redsum[1][row] + redsum[2][row] + redsum[3][row];
      ps[mt][r] = 1.0f / gs;
    }
#pragma unroll
  for (int nt = 0; nt < 4; nt++) {
    int q = 64 * wv + nt * 16 + cl;
#pragma unroll
    for (int mt = 0; mt < 2; mt++)
#pragma unroll
      for (int r = 0; r < 4; r++) {
        int row = p0 + mt * 16 + 4 * h + r;
        attn[(size_t)bn * 65536 + row * 256 + q] = (bf16)(acc[mt][nt][r] * ps[mt][r]);
      }
  }
}

// ---------------- K2t: V transpose (token-major V -> Vq[bn][c][q]) ----------------
// grid 8192; bn = bx&63 for XCD co-location.
__global__ __launch_bounds__(256) void k2t_transpose(
    const bf16* __restrict__ Vtok, bf16* __restrict__ Vq)
{
  const int bx = blockIdx.x;
  const int bn = bx & 63;
  const int r2 = bx >> 6;                  // 0..127
  const int q0 = (r2 & 3) * 64;
  const int c0 = (r2 >> 2) * 64;           // c = sxy*32 + dk
  const int b = bn >> 3, n = bn & 7;
  __shared__ unsigned short tile[64][65];
  const unsigned short* src = (const unsigned short*)Vtok;
  unsigned short* dst = (unsigned short*)Vq + (size_t)bn * 524288;
  {
    const int q = threadIdx.x >> 3;            // 0..31
    const int cj = (threadIdx.x & 7) * 8;
    const int c = c0 + cj;
    const int sxy = c >> 5, dk0 = c & 31;
#pragma unroll
    for (int it = 0; it < 2; ++it) {
      int qq = q + it * 32;
      size_t sa = (size_t)((b * 256 + q0 + qq) * 64 + sxy) * 256 + n * 32 + dk0;
      ushort8 s = *reinterpret_cast<const ushort8*>(src + sa);
#pragma unroll
      for (int j = 0; j < 8; j++) tile[qq][cj + j] = s[j];
    }
  }
  __syncthreads();
  {
    const int crow = threadIdx.x >> 2;         // 0..63
    const int qj = (threadIdx.x & 3) * 8;
#pragma unroll
    for (int it = 0; it < 2; ++it) {
      int qq = qj + it * 32;
      ushort8 sv;
#pragma unroll
      for (int j = 0; j < 8; j++) sv[j] = tile[qq + j][crow];
      *reinterpret_cast<ushort8*>(dst + (size_t)(c0 + crow) * 256 + q0 + qq) = sv;
    }
  }
}

// ---------------- K2b: O = attn @ V (k1-recipe) ----------------
// grid 2048 = 64 bn (low bits) x 4 ptiles x 8 ctiles; block 512 (8 waves).
// A = attn 64x256 tile staged to swizzled LDS via global_load_lds (bf16 source).
__global__ __launch_bounds__(512, 6) void k2b_pv(
    const bf16* __restrict__ attn, const bf16* __restrict__ Vq,
    bf16* __restrict__ yhat)
{
  __shared__ bf16 As[64 * 256];         // 32KB
  const int bx = blockIdx.x;
  const int bn = bx & 63;
  const int r2 = bx >> 6;               // 0..31
  const int p0 = (r2 & 3) * 64;
  const int c0 = (r2 >> 2) * 256;
  const int b = bn >> 3, n = bn & 7;
  const int tid = threadIdx.x;
  const int lane = tid & 63;
  const int w = tid >> 6;               // wave -> 32-c slice of ctile
  const int h = lane >> 4, cl = lane & 15;
  const int c7 = cl & 7;

  const bf16* Ab = attn + (size_t)bn * 65536 + (size_t)p0 * 256;
  const bf16* Vb = Vq + (size_t)bn * 524288;

  // stage A tile: linear LDS dest granule L, pre-swizzled source granule
#pragma unroll
  for (int i = 0; i < 4; ++i) {
    int L = (i * 8 + w) * 64 + lane;
    int S = (L & ~7) | ((L ^ (L >> 5)) & 7);
    gload_lds16(Ab + (size_t)S * 8, &As[(size_t)(i * 8 + w) * 64 * 8]);
  }
  __syncthreads();

  floatx4 acc[4][2];
#pragma unroll
  for (int i = 0; i < 4; i++)
#pragma unroll
    for (int j = 0; j < 2; j++) acc[i][j] = (floatx4)0.0f;

#pragma unroll 2
  for (int kk = 0; kk < 8; ++kk) {
    bf16x8 a[4];
#pragma unroll
    for (int mt = 0; mt < 4; mt++) {
      int rr = mt * 16 + cl;
      int G = rr * 32 + kk * 4 + h;
      int Gp = (G & ~7) | ((G ^ c7) & 7);
      a[mt] = *reinterpret_cast<const bf16x8*>(&As[Gp * 8]);
    }
    bf16x8 b0 = *reinterpret_cast<const bf16x8*>(
        Vb + (size_t)(c0 + w * 32 + cl) * 256 + kk * 32 + 8 * h);
    bf16x8 b1 = *reinterpret_cast<const bf16x8*>(
        Vb + (size_t)(c0 + w * 32 + 16 + cl) * 256 + kk * 32 + 8 * h);
#pragma unroll
    for (int mt = 0; mt < 4; mt++) acc[mt][0] = mfma16(a[mt], b0, acc[mt][0]);
#pragma unroll
    for (int mt = 0; mt < 4; mt++) acc[mt][1] = mfma16(a[mt], b1, acc[mt][1]);
  }

  // token-major epilogue
#pragma unroll
  for (int nt = 0; nt < 2; nt++) {
    const int cg = c0 + w * 32 + nt * 16 + cl;
    const int dk = cg & 31, sxy = cg >> 5;
#pragma unroll
    for (int mt = 0; mt < 4; mt++)
#pragma unroll
      for (int r = 0; r < 4; r++) {
        int p = p0 + mt * 16 + 4 * h + r;
        size_t t = (size_t)((b * 256 + p) * 64) + sxy;
        yhat[t * 256 + n * 32 + dk] = (bf16)acc[mt][nt][r];
      }
  }
}

// ---------------- K3: output projection (k1-recipe) ----------------
// grid 2048; block 512 (8 waves, 32-j slices); t-tile 64.
__global__ __launch_bounds__(512, 6) void k3_out(
    const bf16* __restrict__ yhat, const bf16* __restrict__ Wk3,
    const float* __restrict__ bo, float* __restrict__ outp)
{
  __shared__ bf16 As[64 * 256];         // 32KB
  const int t0 = blockIdx.x * 64;
  const int tid = threadIdx.x;
  const int lane = tid & 63;
  const int w = tid >> 6;
  const int h = lane >> 4, cl = lane & 15;
  const int c7 = cl & 7;

  const bf16* Ab = yhat + (size_t)t0 * 256;

#pragma unroll
  for (int i = 0; i < 4; ++i) {
    int L = (i * 8 + w) * 64 + lane;
    int S = (L & ~7) | ((L ^ (L >> 5)) & 7);
    gload_lds16(Ab + (size_t)S * 8, &As[(size_t)(i * 8 + w) * 64 * 8]);
  }
  __syncthreads();

  floatx4 acc[4][2];
#pragma unroll
  for (int i = 0; i < 4; i++)
#pragma unroll
    for (int j = 0; j < 2; j++) acc[i][j] = (floatx4)0.0f;

#pragma unroll 2
  for (int kk = 0; kk < 8; ++kk) {
    bf16x8 a[4];
#pragma unroll
    for (int mt = 0; mt < 4; mt++) {
      int rr = mt * 16 + cl;
      int G = rr * 32 + kk * 4 + h;
      int Gp = (G & ~7) | ((G ^ c7) & 7);
      a[mt] = *reinterpret_cast<const bf16x8*>(&As[Gp * 8]);
    }
    bf16x8 b0 = *reinterpret_cast<const bf16x8*>(
        Wk3 + ((size_t)(kk * 16 + w * 2 + 0) * 64 + lane) * 8);
    bf16x8 b1 = *reinterpret_cast<const bf16x8*>(
        Wk3 + ((size_t)(kk * 16 + w * 2 + 1) * 64 + lane) * 8);
#pragma unroll
    for (int mt = 0; mt < 4; mt++) acc[mt][0] = mfma16(a[mt], b0, acc[mt][0]);
#pragma unroll
    for (int mt = 0; mt < 4; mt++) acc[mt][1] = mfma16(a[mt], b1, acc[mt][1]);
  }

#pragma unroll
  for (int nt = 0; nt < 2; nt++) {
    const int j = w * 32 + nt * 16 + cl;
    const float bb = bo[j];
#pragma unroll
    for (int mt = 0; mt < 4; mt++)
#pragma unroll
      for (int r = 0; r < 4; r++)
        outp[(size_t)(t0 + mt * 16 + 4 * h + r) * 256 + j] = acc[mt][nt][r] + bb;
  }
}

// ---------------- launch ----------------
extern "C" void kernel_launch(void* const* d_in, const int* in_sizes, int n_in,
                              void* d_out, int out_size, void* d_ws, size_t ws_size,
                              hipStream_t stream) {
  const float* x  = (const float*)d_in[0];
  const float* Wq = (const float*)d_in[1];
  const float* bq = (const float*)d_in[2];
  const float* Wk = (const float*)d_in[3];
  const float* bk = (const float*)d_in[4];
  const float* Wv = (const float*)d_in[5];
  const float* bv = (const float*)d_in[6];
  const float* Wo = (const float*)d_in[7];
  const float* bo = (const float*)d_in[8];
  float* outp = (float*)d_out;

  char* ws = (char*)d_ws;
  const size_t SZ_QKV = 67108864;   // 131072*256 * 2B
  size_t off = 0;
  bf16* Qt   = (bf16*)(ws + off); off += SZ_QKV;
  bf16* Kt   = (bf16*)(ws + off); off += SZ_QKV;
  bf16* Vtok = (bf16*)(ws + off); off += SZ_QKV;
  bf16* attn = (bf16*)(ws + off); off += 8388608;
  bf16* Wp   = (bf16*)(ws + off); off += 393216;   // qkv fragment packs
  bf16* Wk3  = (bf16*)(ws + off); off += 131072;   // k3 fragment pack
  float* biasp = (float*)(ws + off); off += 3072;
  if (ws_size < off) return;        // workspace too small: bail cleanly

  bf16* yhat = Qt;                  // Qt dead after k2a
  bf16* Vq   = Kt;                  // Kt dead after k2a (k2t runs after k2a)

  k0_prep<<<64, 256, 0, stream>>>(Wq, bq, Wk, bk, Wv, bv, Wo, Wp, Wk3, biasp);
  k1_qkv<<<dim3(2048, 3), 512, 0, stream>>>(x, Wp, biasp, Qt, Kt, Vtok);
  k2a_scores<<<512, 256, 0, stream>>>(Qt, Kt, attn);
  k2t_transpose<<<8192, 256, 0, stream>>>(Vtok, Vq);
  k2b_pv<<<2048, 512, 0, stream>>>(attn, Vq, yhat);
  k3_out<<<2048, 512, 0, stream>>>(yhat, Wk3, bo, outp);
}